// Round 1
// baseline (933.931 us; speedup 1.0000x reference)
//
#include <hip/hip_runtime.h>
#include <math.h>

// Problem constants (B=2, L=2048, D=1024, H=16, HD=64)
#define NB_B 2
#define NB_L 2048
#define NB_D 1024
#define NB_H 16
#define NB_HD 64
#define GM (NB_B * NB_L)   // 4096 rows
#define GN (3 * NB_D)      // 3072 cols (q|k|v each 1024, head-major within)
#define GK NB_D            // 1024

// ---------------------------------------------------------------------------
// Kernel 1: fp32 GEMM  QKV[4096,3072] = X[4096,1024] @ W[1024,3072]
// 128x128 tile, BK=16, 256 threads, 8x8 per thread.
// Per-thread cols split as {tx*4..+3} and {64+tx*4..+3} so Bs b128 reads are
// 2-way bank aliased (free); As reads are 4-address broadcast (free).
// ---------------------------------------------------------------------------
__global__ __launch_bounds__(256) void qkv_gemm_f32(
    const float* __restrict__ X, const float* __restrict__ W,
    float* __restrict__ QKV)
{
    __shared__ float As[16][132];  // [k][m], transposed A tile (132*4 = 16B-mult)
    __shared__ float Bs[16][132];  // [k][n]

    const int tid = threadIdx.x;
    const int tx  = tid & 15;
    const int ty  = tid >> 4;
    const int row0 = blockIdx.y * 128;
    const int col0 = blockIdx.x * 128;

    float acc[8][8];
#pragma unroll
    for (int i = 0; i < 8; ++i)
#pragma unroll
        for (int j = 0; j < 8; ++j) acc[i][j] = 0.f;

    const int ar  = tid >> 1;          // A row this thread stages (0..127)
    const int ak0 = (tid & 1) * 8;     // A k-offset 0 or 8
    const int bc0 = tid * 2;           // B chunk ids

    for (int k0 = 0; k0 < GK; k0 += 16) {
        // stage A (128x16) -> As[k][m]
#pragma unroll
        for (int q = 0; q < 2; ++q) {
            const int ak = ak0 + q * 4;
            const float4 v = *(const float4*)(X + (size_t)(row0 + ar) * GK + k0 + ak);
            As[ak + 0][ar] = v.x;
            As[ak + 1][ar] = v.y;
            As[ak + 2][ar] = v.z;
            As[ak + 3][ar] = v.w;
        }
        // stage B (16x128) -> Bs[k][n], fully coalesced global reads
#pragma unroll
        for (int q = 0; q < 2; ++q) {
            const int c  = bc0 + q;
            const int br = c >> 5;
            const int bc = (c & 31) * 4;
            *(float4*)(&Bs[br][bc]) =
                *(const float4*)(W + (size_t)(k0 + br) * GN + col0 + bc);
        }
        __syncthreads();

#pragma unroll
        for (int kk = 0; kk < 16; ++kk) {
            float a[8], b[8];
            *(float4*)(a)     = *(const float4*)(&As[kk][ty * 8]);
            *(float4*)(a + 4) = *(const float4*)(&As[kk][ty * 8 + 4]);
            *(float4*)(b)     = *(const float4*)(&Bs[kk][tx * 4]);
            *(float4*)(b + 4) = *(const float4*)(&Bs[kk][64 + tx * 4]);
#pragma unroll
            for (int i = 0; i < 8; ++i)
#pragma unroll
                for (int j = 0; j < 8; ++j)
                    acc[i][j] = fmaf(a[i], b[j], acc[i][j]);
        }
        __syncthreads();
    }

#pragma unroll
    for (int i = 0; i < 8; ++i) {
        float* p = QKV + (size_t)(row0 + ty * 8 + i) * GN + col0;
        *(float4*)(p + tx * 4)      = make_float4(acc[i][0], acc[i][1], acc[i][2], acc[i][3]);
        *(float4*)(p + 64 + tx * 4) = make_float4(acc[i][4], acc[i][5], acc[i][6], acc[i][7]);
    }
}

// ---------------------------------------------------------------------------
// Kernel 2: causal flash attention, fp32.
// grid = (L/64 q-tiles, H, B), 256 threads. 64x64 k-tiles, only kt <= qt.
// Thread (rg,cg) owns S rows rg*4..+3, cols cg*4..+3; O rows rg*4..+3,
// d-cols cg*4..+3. Online softmax: 16-lane shfl_xor row reductions.
// All LDS strides = 68 floats (272 B: 16B-aligned rows, <=2-way on hot reads).
// ---------------------------------------------------------------------------
__global__ __launch_bounds__(256) void attn_f32(
    const float* __restrict__ QKV, float* __restrict__ Out)
{
    const int qt  = blockIdx.x;   // 0..31
    const int h   = blockIdx.y;   // 0..15
    const int b   = blockIdx.z;   // 0..1
    const int tid = threadIdx.x;
    const int rg  = tid >> 4;     // 0..15 -> rows rg*4..+3
    const int cg  = tid & 15;     // 0..15 -> cols cg*4..+3

    __shared__ float QT[64][68];  // [d][qrow], pre-scaled by 1/8
    __shared__ float KT[64][68];  // [d][kcol]
    __shared__ float Vs[64][68];  // [krow][d]
    __shared__ float PT[64][68];  // [kcol][qrow]

    const int lr = tid >> 2;      // staging row 0..63
    const int lc = tid & 3;       // staging 16-float group

    const size_t rowbase = ((size_t)b * NB_L) * (size_t)GN;

    // stage Q tile (scaled by 1/sqrt(hd) = 0.125)
    {
        const float* src = QKV + rowbase + (size_t)(qt * 64 + lr) * GN + h * NB_HD + lc * 16;
#pragma unroll
        for (int u = 0; u < 4; ++u) {
            const float4 v = *(const float4*)(src + u * 4);
            const int d0 = lc * 16 + u * 4;
            QT[d0 + 0][lr] = v.x * 0.125f;
            QT[d0 + 1][lr] = v.y * 0.125f;
            QT[d0 + 2][lr] = v.z * 0.125f;
            QT[d0 + 3][lr] = v.w * 0.125f;
        }
    }

    float m_i[4], l_i[4], o[4][4];
#pragma unroll
    for (int i = 0; i < 4; ++i) {
        m_i[i] = -INFINITY;
        l_i[i] = 0.f;
#pragma unroll
        for (int c = 0; c < 4; ++c) o[i][c] = 0.f;
    }

    for (int kt = 0; kt <= qt; ++kt) {
        // stage K^T and V for this k-tile
        {
            const float* ksrc = QKV + rowbase + (size_t)(kt * 64 + lr) * GN + NB_D     + h * NB_HD + lc * 16;
            const float* vsrc = QKV + rowbase + (size_t)(kt * 64 + lr) * GN + 2 * NB_D + h * NB_HD + lc * 16;
#pragma unroll
            for (int u = 0; u < 4; ++u) {
                const float4 kv = *(const float4*)(ksrc + u * 4);
                const int d0 = lc * 16 + u * 4;
                KT[d0 + 0][lr] = kv.x;
                KT[d0 + 1][lr] = kv.y;
                KT[d0 + 2][lr] = kv.z;
                KT[d0 + 3][lr] = kv.w;
                *(float4*)(&Vs[lr][d0]) = *(const float4*)(vsrc + u * 4);
            }
        }
        __syncthreads();

        // S = (Q/8) K^T, 4x4 per thread
        float s[4][4];
#pragma unroll
        for (int i = 0; i < 4; ++i)
#pragma unroll
            for (int j = 0; j < 4; ++j) s[i][j] = 0.f;

        for (int k = 0; k < 64; ++k) {
            float qv[4], kv[4];
            *(float4*)qv = *(const float4*)(&QT[k][rg * 4]);
            *(float4*)kv = *(const float4*)(&KT[k][cg * 4]);
#pragma unroll
            for (int i = 0; i < 4; ++i)
#pragma unroll
                for (int j = 0; j < 4; ++j)
                    s[i][j] = fmaf(qv[i], kv[j], s[i][j]);
        }

        // causal mask (diagonal tile only)
        if (kt == qt) {
#pragma unroll
            for (int i = 0; i < 4; ++i)
#pragma unroll
                for (int j = 0; j < 4; ++j)
                    if (cg * 4 + j > rg * 4 + i) s[i][j] = -INFINITY;
        }

        // online softmax per owned row
#pragma unroll
        for (int i = 0; i < 4; ++i) {
            float tmax = fmaxf(fmaxf(s[i][0], s[i][1]), fmaxf(s[i][2], s[i][3]));
            tmax = fmaxf(tmax, __shfl_xor(tmax, 1));
            tmax = fmaxf(tmax, __shfl_xor(tmax, 2));
            tmax = fmaxf(tmax, __shfl_xor(tmax, 4));
            tmax = fmaxf(tmax, __shfl_xor(tmax, 8));
            const float mnew  = fmaxf(m_i[i], tmax);
            const float alpha = __expf(m_i[i] - mnew);   // first tile: exp(-inf)=0
            m_i[i] = mnew;
            float rsum = 0.f;
#pragma unroll
            for (int j = 0; j < 4; ++j) {
                const float p = __expf(s[i][j] - mnew);  // masked -> exp(-inf)=0
                s[i][j] = p;
                rsum += p;
            }
            rsum += __shfl_xor(rsum, 1);
            rsum += __shfl_xor(rsum, 2);
            rsum += __shfl_xor(rsum, 4);
            rsum += __shfl_xor(rsum, 8);
            l_i[i] = l_i[i] * alpha + rsum;
#pragma unroll
            for (int c = 0; c < 4; ++c) o[i][c] *= alpha;
        }

        // write P^T to LDS: PT[col][rows rg*4..+3] as b128 (col-major for PV reads)
#pragma unroll
        for (int j = 0; j < 4; ++j)
            *(float4*)(&PT[cg * 4 + j][rg * 4]) =
                make_float4(s[0][j], s[1][j], s[2][j], s[3][j]);
        __syncthreads();

        // O += P V
        for (int j = 0; j < 64; ++j) {
            float pv[4], vv[4];
            *(float4*)pv = *(const float4*)(&PT[j][rg * 4]);
            *(float4*)vv = *(const float4*)(&Vs[j][cg * 4]);
#pragma unroll
            for (int i = 0; i < 4; ++i)
#pragma unroll
                for (int c = 0; c < 4; ++c)
                    o[i][c] = fmaf(pv[i], vv[c], o[i][c]);
        }
        __syncthreads();  // protect KT/Vs/PT before next tile's staging
    }

    // epilogue: normalize and store [B, L, D]
#pragma unroll
    for (int i = 0; i < 4; ++i) {
        const float inv = 1.0f / l_i[i];
        float* dst = Out + ((size_t)b * NB_L + qt * 64 + rg * 4 + i) * NB_D + h * NB_HD + cg * 4;
        *(float4*)dst = make_float4(o[i][0] * inv, o[i][1] * inv, o[i][2] * inv, o[i][3] * inv);
    }
}

// ---------------------------------------------------------------------------
extern "C" void kernel_launch(void* const* d_in, const int* in_sizes, int n_in,
                              void* d_out, int out_size, void* d_ws, size_t ws_size,
                              hipStream_t stream)
{
    const float* x = (const float*)d_in[0];   // [B, L, D] fp32
    const float* w = (const float*)d_in[1];   // [D, 3D] fp32
    float* out = (float*)d_out;               // [B, L, D] fp32
    float* qkv = (float*)d_ws;                // needs 4096*3072*4 = 50.3 MB scratch

    qkv_gemm_f32<<<dim3(GN / 128, GM / 128), 256, 0, stream>>>(x, w, qkv);
    attn_f32<<<dim3(NB_L / 64, NB_H, NB_B), 256, 0, stream>>>(qkv, out);
}

// Round 2
// 235.856 us; speedup vs baseline: 3.9597x; 3.9597x over previous
//
#include <hip/hip_runtime.h>
#include <hip/hip_bf16.h>
#include <math.h>

// B=2, L=2048, D=1024, H=16, HD=64
#define NB_L 2048
#define GM 4096          // B*L rows
#define GN 3072          // 3*D cols (q|k|v, head-major inside)
#define GK 1024

typedef float  f4v __attribute__((ext_vector_type(4)));
typedef short  s4v __attribute__((ext_vector_type(4)));
typedef short  s8v __attribute__((ext_vector_type(8)));

#define MFMA_16x16x32(a, b, c) __builtin_amdgcn_mfma_f32_16x16x32_bf16((a), (b), (c), 0, 0, 0)
#define MFMA_16x16x16(a, b, c) __builtin_amdgcn_mfma_f32_16x16x16bf16_1k((a), (b), (c), 0, 0, 0)

static __device__ __forceinline__ unsigned int bfpk(float a, float b) {
    __hip_bfloat162 h = __float22bfloat162_rn(float2{a, b});
    union { __hip_bfloat162 h2; unsigned int u; } cv; cv.h2 = h; return cv.u;
}
static __device__ __forceinline__ unsigned short bf1(float a) {
    union { __hip_bfloat16 h; unsigned short u; } cv; cv.h = __float2bfloat16(a); return cv.u;
}

// ---------------------------------------------------------------------------
// Convert X [4096,1024] f32 -> bf16 (same layout). 8 elements/thread.
// ---------------------------------------------------------------------------
__global__ __launch_bounds__(256) void conv_x(const float* __restrict__ X, ushort* __restrict__ Xb) {
    const int i = blockIdx.x * 256 + threadIdx.x;      // chunk of 8
    const float4 f0 = ((const float4*)X)[2 * i];
    const float4 f1 = ((const float4*)X)[2 * i + 1];
    uint4 u;
    u.x = bfpk(f0.x, f0.y); u.y = bfpk(f0.z, f0.w);
    u.z = bfpk(f1.x, f1.y); u.w = bfpk(f1.z, f1.w);
    ((uint4*)Xb)[i] = u;
}

// ---------------------------------------------------------------------------
// Convert+transpose W [1024,3072] f32 -> Wt [3072,1024] bf16 (k contiguous).
// 64x64 tiles via LDS.
// ---------------------------------------------------------------------------
__global__ __launch_bounds__(256) void conv_wt(const float* __restrict__ W, ushort* __restrict__ Wt) {
    __shared__ __align__(16) ushort T[64][72];
    const int t = threadIdx.x;
    const int k0 = blockIdx.x * 64, n0 = blockIdx.y * 64;
    {
        const int kr = t >> 2, nc0 = (t & 3) * 16;
        const float* src = W + (size_t)(k0 + kr) * GN + n0 + nc0;
#pragma unroll
        for (int u = 0; u < 4; ++u) {
            const float4 v = *(const float4*)(src + 4 * u);
            T[nc0 + 4 * u + 0][kr] = bf1(v.x);
            T[nc0 + 4 * u + 1][kr] = bf1(v.y);
            T[nc0 + 4 * u + 2][kr] = bf1(v.z);
            T[nc0 + 4 * u + 3][kr] = bf1(v.w);
        }
    }
    __syncthreads();
    {
        const int nr = t >> 2, kc0 = (t & 3) * 16;
        ushort* dst = Wt + (size_t)(n0 + nr) * GK + k0 + kc0;
        *(s8v*)dst       = *(const s8v*)&T[nr][kc0];
        *(s8v*)(dst + 8) = *(const s8v*)&T[nr][kc0 + 8];
    }
}

// ---------------------------------------------------------------------------
// bf16 MFMA GEMM: Qkv[4096,3072] = Xb[4096,1024] x Wt^T, output bf16.
// 128x128 tile, BK=32, 256 thr (4 waves 2x2, each 64x64 = 4x4 MFMA 16x16x32).
// LDS granule-major [k2][m][8] (16B granules) -> conflict-free b128 frag reads.
// Software-pipelined: next iter's global loads issued before compute.
// ---------------------------------------------------------------------------
__global__ __launch_bounds__(256) void qkv_gemm_bf16(
    const ushort* __restrict__ Xb, const ushort* __restrict__ Wt, ushort* __restrict__ Qkv)
{
    __shared__ __align__(16) ushort As[4][128][8];
    __shared__ __align__(16) ushort Bs[4][128][8];
    const int tid = threadIdx.x;
    const int row0 = blockIdx.y * 128, col0 = blockIdx.x * 128;
    const int mA = tid & 127, k2a = tid >> 7;       // granules (mA,k2a) and (mA,k2a+2)
    const int lane = tid & 63, w = tid >> 6;
    const int wr = w >> 1, wc = w & 1, lq = lane & 15, quad = lane >> 4;

    f4v acc[4][4];
#pragma unroll
    for (int g = 0; g < 4; ++g)
#pragma unroll
        for (int j = 0; j < 4; ++j) acc[g][j] = 0.f;

    const ushort* ga0 = Xb + (size_t)(row0 + mA) * GK + k2a * 8;
    const ushort* gb0 = Wt + (size_t)(col0 + mA) * GK + k2a * 8;
    s8v ra0 = *(const s8v*)ga0, ra1 = *(const s8v*)(ga0 + 16);
    s8v rb0 = *(const s8v*)gb0, rb1 = *(const s8v*)(gb0 + 16);

    for (int it = 0; it < 32; ++it) {
        __syncthreads();
        *(s8v*)&As[k2a][mA][0]     = ra0;
        *(s8v*)&As[k2a + 2][mA][0] = ra1;
        *(s8v*)&Bs[k2a][mA][0]     = rb0;
        *(s8v*)&Bs[k2a + 2][mA][0] = rb1;
        __syncthreads();
        if (it + 1 < 32) {
            const int k0 = (it + 1) * 32;
            ra0 = *(const s8v*)(ga0 + k0); ra1 = *(const s8v*)(ga0 + k0 + 16);
            rb0 = *(const s8v*)(gb0 + k0); rb1 = *(const s8v*)(gb0 + k0 + 16);
        }
        s8v af[4], bfr[4];
#pragma unroll
        for (int g = 0; g < 4; ++g) af[g]  = *(const s8v*)&As[quad][wr * 64 + g * 16 + lq][0];
#pragma unroll
        for (int j = 0; j < 4; ++j) bfr[j] = *(const s8v*)&Bs[quad][wc * 64 + j * 16 + lq][0];
#pragma unroll
        for (int g = 0; g < 4; ++g)
#pragma unroll
            for (int j = 0; j < 4; ++j)
                acc[g][j] = MFMA_16x16x32(af[g], bfr[j], acc[g][j]);
    }

    // epilogue: C/D layout row=4*quad+r, col=lq
#pragma unroll
    for (int g = 0; g < 4; ++g)
#pragma unroll
        for (int j = 0; j < 4; ++j) {
            const int col = col0 + wc * 64 + j * 16 + lq;
#pragma unroll
            for (int r = 0; r < 4; ++r) {
                const int row = row0 + wr * 64 + g * 16 + quad * 4 + r;
                Qkv[(size_t)row * GN + col] = bf1(acc[g][j][r]);
            }
        }
}

// ---------------------------------------------------------------------------
// Flash attention, bf16 MFMA.
// Block = 128 thr (2 waves), Q-tile = 128 rows (wave w owns rows w*64..+63).
// Per k-tile (64 kcols): S^T = K·Q^T via mfma 16x16x32 (C cols = q-rows ->
// softmax stats broadcast per lane-column); S^T C-regs feed PV B-operand of
// mfma 16x16x16 directly (C layout == B layout for K=16). V transposed into
// LDS at stage time for the PV A-operand. Q frags preloaded in registers.
// ---------------------------------------------------------------------------
#define SCALE_L2E 0.180336880f   // 0.125 * log2(e)

__global__ __launch_bounds__(128) void attn_bf16(
    const ushort* __restrict__ Qkv, float* __restrict__ Out)
{
    __shared__ __align__(16) ushort Ks[64][72];
    __shared__ __align__(16) ushort Vt[64][72];

    // load-balance swizzle: pair (qt, 15-qt) across dispatch halves
    const int x = blockIdx.x;
    const int pair = x & 255, sel = x >> 8;
    const int qt = sel ? (15 - (pair >> 5)) : (pair >> 5);
    const int bh = pair & 31;
    const int h = bh & 15, b = bh >> 4;

    const int tid = threadIdx.x;
    const int w = tid >> 6, lane = tid & 63;
    const int lq = lane & 15, quad = lane >> 4;
    const int boff = b * NB_L;
    const int qrow_base = qt * 128 + w * 64;

    // Q fragments in registers: qf[qg][s], k = 32s + 8*quad + jj, row = qg*16+lq
    s8v qf[4][2];
#pragma unroll
    for (int qg = 0; qg < 4; ++qg)
#pragma unroll
        for (int s = 0; s < 2; ++s)
            qf[qg][s] = *(const s8v*)(Qkv + (size_t)(boff + qrow_base + qg * 16 + lq) * GN
                                      + h * 64 + s * 32 + quad * 8);

    f4v o[4][4];   // O^T tiles [dg][qg], row=d=4*quad+r, col=q=lq
#pragma unroll
    for (int dg = 0; dg < 4; ++dg)
#pragma unroll
        for (int qg = 0; qg < 4; ++qg) o[dg][qg] = 0.f;
    float m_s[4], l_s[4];
#pragma unroll
    for (int qg = 0; qg < 4; ++qg) { m_s[qg] = -INFINITY; l_s[qg] = 0.f; }

    const int ktmax = 2 * qt + 1;
    for (int kt = 0; kt <= ktmax; ++kt) {
        // ---- stage K (row-major) and V^T into LDS ----
        s8v kreg[4];
        const int krow = tid >> 3, kchunk = tid & 7;
#pragma unroll
        for (int i = 0; i < 4; ++i)
            kreg[i] = *(const s8v*)(Qkv + (size_t)(boff + kt * 64 + krow + 16 * i) * GN
                                    + 1024 + h * 64 + kchunk * 8);
        const int pr = tid >> 2, dc0 = (tid & 3) * 16;
        const ushort* v0p = Qkv + (size_t)(boff + kt * 64 + 2 * pr) * GN + 2048 + h * 64 + dc0;
        const ushort* v1p = v0p + GN;
        s8v v0a = *(const s8v*)v0p, v0b = *(const s8v*)(v0p + 8);
        s8v v1a = *(const s8v*)v1p, v1b = *(const s8v*)(v1p + 8);

        __syncthreads();   // previous compute done reading LDS
#pragma unroll
        for (int i = 0; i < 4; ++i)
            *(s8v*)&Ks[krow + 16 * i][kchunk * 8] = kreg[i];
#pragma unroll
        for (int j = 0; j < 16; ++j) {
            const unsigned short lo = (unsigned short)((j < 8) ? v0a[j] : v0b[j - 8]);
            const unsigned short hi = (unsigned short)((j < 8) ? v1a[j] : v1b[j - 8]);
            *(unsigned int*)&Vt[dc0 + j][2 * pr] = (unsigned int)lo | ((unsigned int)hi << 16);
        }
        __syncthreads();

        if (kt <= 2 * qt + w) {
            // ---- S^T = K · Q^T ----
            f4v st[4][4];
#pragma unroll
            for (int kg = 0; kg < 4; ++kg)
#pragma unroll
                for (int qg = 0; qg < 4; ++qg) st[kg][qg] = 0.f;
#pragma unroll
            for (int kg = 0; kg < 4; ++kg) {
#pragma unroll
                for (int s = 0; s < 2; ++s) {
                    const s8v af = *(const s8v*)&Ks[kg * 16 + lq][s * 32 + quad * 8];
#pragma unroll
                    for (int qg = 0; qg < 4; ++qg)
                        st[kg][qg] = MFMA_16x16x32(af, qf[qg][s], st[kg][qg]);
                }
            }
            // ---- causal mask (diagonal k-tile of this wave only) ----
            if (kt == 2 * qt + w) {
#pragma unroll
                for (int kg = 0; kg < 4; ++kg)
#pragma unroll
                    for (int qg = 0; qg < 4; ++qg) {
                        const int qrow = qrow_base + qg * 16 + lq;
#pragma unroll
                        for (int r = 0; r < 4; ++r)
                            if (kt * 64 + kg * 16 + quad * 4 + r > qrow)
                                st[kg][qg][r] = -INFINITY;
                    }
            }
            // ---- online softmax per q-column (stats broadcast per lane) ----
#pragma unroll
            for (int qg = 0; qg < 4; ++qg) {
                float mx = -INFINITY;
#pragma unroll
                for (int kg = 0; kg < 4; ++kg)
#pragma unroll
                    for (int r = 0; r < 4; ++r) mx = fmaxf(mx, st[kg][qg][r]);
                mx = fmaxf(mx, __shfl_xor(mx, 16));
                mx = fmaxf(mx, __shfl_xor(mx, 32));
                const float mnew = fmaxf(m_s[qg], mx);
                const float alpha = exp2f((m_s[qg] - mnew) * SCALE_L2E);
                m_s[qg] = mnew;
                const float mc = mnew * SCALE_L2E;
                float sum = 0.f;
#pragma unroll
                for (int kg = 0; kg < 4; ++kg)
#pragma unroll
                    for (int r = 0; r < 4; ++r) {
                        const float p = exp2f(fmaf(st[kg][qg][r], SCALE_L2E, -mc));
                        st[kg][qg][r] = p;
                        sum += p;
                    }
                sum += __shfl_xor(sum, 16);
                sum += __shfl_xor(sum, 32);
                l_s[qg] = l_s[qg] * alpha + sum;
#pragma unroll
                for (int dg = 0; dg < 4; ++dg) o[dg][qg] *= alpha;
            }
            // ---- O^T += V^T · P^T (P fed straight from S^T C-regs) ----
#pragma unroll
            for (int ks = 0; ks < 4; ++ks) {
                s4v pb[4];
#pragma unroll
                for (int qg = 0; qg < 4; ++qg) {
                    union { s4v v; uint2 u; } c;
                    c.u.x = bfpk(st[ks][qg][0], st[ks][qg][1]);
                    c.u.y = bfpk(st[ks][qg][2], st[ks][qg][3]);
                    pb[qg] = c.v;
                }
#pragma unroll
                for (int dg = 0; dg < 4; ++dg) {
                    const s4v va = *(const s4v*)&Vt[dg * 16 + lq][ks * 16 + quad * 4];
#pragma unroll
                    for (int qg = 0; qg < 4; ++qg)
                        o[dg][qg] = MFMA_16x16x16(va, pb[qg], o[dg][qg]);
                }
            }
        }
    }

    // ---- epilogue: normalize, transpose back via layout, store f32 ----
#pragma unroll
    for (int qg = 0; qg < 4; ++qg) {
        const float inv = 1.0f / l_s[qg];
        const size_t row = (size_t)(boff + qrow_base + qg * 16 + lq);
#pragma unroll
        for (int dg = 0; dg < 4; ++dg) {
            float4 v = make_float4(o[dg][qg][0] * inv, o[dg][qg][1] * inv,
                                   o[dg][qg][2] * inv, o[dg][qg][3] * inv);
            *(float4*)(Out + row * 1024 + h * 64 + dg * 16 + quad * 4) = v;
        }
    }
}

// ---------------------------------------------------------------------------
extern "C" void kernel_launch(void* const* d_in, const int* in_sizes, int n_in,
                              void* d_out, int out_size, void* d_ws, size_t ws_size,
                              hipStream_t stream)
{
    const float* x = (const float*)d_in[0];   // [2,2048,1024] f32
    const float* wq = (const float*)d_in[1];  // [1024,3072] f32
    float* out = (float*)d_out;               // [2,2048,1024] f32

    ushort* ws   = (ushort*)d_ws;
    ushort* qkvb = ws;                         // 4096*3072 bf16 = 25.2 MB
    ushort* xb   = ws + (size_t)GM * GN;       // 4096*1024 bf16 =  8.4 MB
    ushort* wt   = xb + (size_t)GM * GK;       // 3072*1024 bf16 =  6.3 MB

    conv_x<<<GM * GK / (256 * 8), 256, 0, stream>>>(x, xb);
    conv_wt<<<dim3(GK / 64, GN / 64), 256, 0, stream>>>(wq, wt);
    qkv_gemm_bf16<<<dim3(GN / 128, GM / 128), 256, 0, stream>>>(xb, wt, qkvb);
    attn_bf16<<<512, 128, 0, stream>>>(qkvb, out);
}

// Round 3
// 203.066 us; speedup vs baseline: 4.5992x; 1.1615x over previous
//
#include <hip/hip_runtime.h>
#include <hip/hip_bf16.h>
#include <math.h>

// B=2, L=2048, D=1024, H=16, HD=64
#define NB_L 2048
#define GM 4096          // B*L rows
#define GN 3072          // 3*D cols (q|k|v, head-major inside)
#define GK 1024
#define NROWS 65536      // B*H*L partial rows per split

typedef float  f4v __attribute__((ext_vector_type(4)));
typedef short  s4v __attribute__((ext_vector_type(4)));
typedef short  s8v __attribute__((ext_vector_type(8)));

#define MFMA_16x16x32(a, b, c) __builtin_amdgcn_mfma_f32_16x16x32_bf16((a), (b), (c), 0, 0, 0)
#define MFMA_16x16x16(a, b, c) __builtin_amdgcn_mfma_f32_16x16x16bf16_1k((a), (b), (c), 0, 0, 0)

static __device__ __forceinline__ unsigned int bfpk(float a, float b) {
    __hip_bfloat162 h = __float22bfloat162_rn(float2{a, b});
    union { __hip_bfloat162 h2; unsigned int u; } cv; cv.h2 = h; return cv.u;
}
static __device__ __forceinline__ unsigned short bf1(float a) {
    union { __hip_bfloat16 h; unsigned short u; } cv; cv.h = __float2bfloat16(a); return cv.u;
}
static __device__ __forceinline__ float bf2f(unsigned short u) {
    union { unsigned int u; float f; } cv; cv.u = ((unsigned int)u) << 16; return cv.f;
}

// async global->LDS, 16B per lane (dest must be wave-uniform base + lane*16)
static __device__ __forceinline__ void gl_lds16(const ushort* g, ushort* l) {
#if defined(__has_builtin) && __has_builtin(__builtin_amdgcn_global_load_lds)
    __builtin_amdgcn_global_load_lds((const __attribute__((address_space(1))) void*)g,
                                     (__attribute__((address_space(3))) void*)l, 16, 0, 0);
#else
    *(s8v*)l = *(const s8v*)g;
#endif
}

// ---------------------------------------------------------------------------
// X [4096,1024] f32 -> bf16
// ---------------------------------------------------------------------------
__global__ __launch_bounds__(256) void conv_x(const float* __restrict__ X, ushort* __restrict__ Xb) {
    const int i = blockIdx.x * 256 + threadIdx.x;
    const float4 f0 = ((const float4*)X)[2 * i];
    const float4 f1 = ((const float4*)X)[2 * i + 1];
    uint4 u;
    u.x = bfpk(f0.x, f0.y); u.y = bfpk(f0.z, f0.w);
    u.z = bfpk(f1.x, f1.y); u.w = bfpk(f1.z, f1.w);
    ((uint4*)Xb)[i] = u;
}

// ---------------------------------------------------------------------------
// W [1024,3072] f32 -> Wt [3072,1024] bf16 (transpose, k contiguous)
// ---------------------------------------------------------------------------
__global__ __launch_bounds__(256) void conv_wt(const float* __restrict__ W, ushort* __restrict__ Wt) {
    __shared__ __align__(16) ushort T[64][72];
    const int t = threadIdx.x;
    const int k0 = blockIdx.x * 64, n0 = blockIdx.y * 64;
    {
        const int kr = t >> 2, nc0 = (t & 3) * 16;
        const float* src = W + (size_t)(k0 + kr) * GN + n0 + nc0;
#pragma unroll
        for (int u = 0; u < 4; ++u) {
            const float4 v = *(const float4*)(src + 4 * u);
            T[nc0 + 4 * u + 0][kr] = bf1(v.x);
            T[nc0 + 4 * u + 1][kr] = bf1(v.y);
            T[nc0 + 4 * u + 2][kr] = bf1(v.z);
            T[nc0 + 4 * u + 3][kr] = bf1(v.w);
        }
    }
    __syncthreads();
    {
        const int nr = t >> 2, kc0 = (t & 3) * 16;
        ushort* dst = Wt + (size_t)(n0 + nr) * GK + k0 + kc0;
        *(s8v*)dst       = *(const s8v*)&T[nr][kc0];
        *(s8v*)(dst + 8) = *(const s8v*)&T[nr][kc0 + 8];
    }
}

// ---------------------------------------------------------------------------
// bf16 MFMA GEMM (m97 structure): 128x128 tile, BK=32, 256 thr, glds16 staging.
// ---------------------------------------------------------------------------
__global__ __launch_bounds__(256) void qkv_gemm_bf16(
    const ushort* __restrict__ Xb, const ushort* __restrict__ Wt, ushort* __restrict__ Qkv)
{
    __shared__ __align__(16) ushort As[4][128][8];
    __shared__ __align__(16) ushort Bs[4][128][8];
    const int tid = threadIdx.x;
    const int row0 = blockIdx.y * 128, col0 = blockIdx.x * 128;
    const int mA = tid & 127, k2a = tid >> 7;
    const int lane = tid & 63, w = tid >> 6;
    const int wr = w >> 1, wc = w & 1, lq = lane & 15, quad = lane >> 4;

    f4v acc[4][4];
#pragma unroll
    for (int g = 0; g < 4; ++g)
#pragma unroll
        for (int j = 0; j < 4; ++j) acc[g][j] = 0.f;

    const ushort* gA = Xb + (size_t)(row0 + mA) * GK + k2a * 8;
    const ushort* gB = Wt + (size_t)(col0 + mA) * GK + k2a * 8;
    ushort* lA0 = &As[k2a][mA][0];
    ushort* lA1 = &As[k2a + 2][mA][0];
    ushort* lB0 = &Bs[k2a][mA][0];
    ushort* lB1 = &Bs[k2a + 2][mA][0];

    for (int it = 0; it < 32; ++it) {
        const int k0 = it * 32;
        __syncthreads();
        gl_lds16(gA + k0, lA0);
        gl_lds16(gA + k0 + 16, lA1);
        gl_lds16(gB + k0, lB0);
        gl_lds16(gB + k0 + 16, lB1);
        __syncthreads();

        s8v af[4], bfr[4];
#pragma unroll
        for (int g = 0; g < 4; ++g) af[g]  = *(const s8v*)&As[quad][wr * 64 + g * 16 + lq][0];
#pragma unroll
        for (int j = 0; j < 4; ++j) bfr[j] = *(const s8v*)&Bs[quad][wc * 64 + j * 16 + lq][0];
#pragma unroll
        for (int g = 0; g < 4; ++g)
#pragma unroll
            for (int j = 0; j < 4; ++j)
                acc[g][j] = MFMA_16x16x32(af[g], bfr[j], acc[g][j]);
    }

#pragma unroll
    for (int g = 0; g < 4; ++g)
#pragma unroll
        for (int j = 0; j < 4; ++j) {
            const int col = col0 + wc * 64 + j * 16 + lq;
#pragma unroll
            for (int r = 0; r < 4; ++r) {
                const int row = row0 + wr * 64 + g * 16 + quad * 4 + r;
                Qkv[(size_t)row * GN + col] = bf1(acc[g][j][r]);
            }
        }
}

// ---------------------------------------------------------------------------
// Flash attention with K-split=2 (flash-decoding). Block = 128 thr (2 waves),
// q-tile 128 (wave w owns 64 q-rows). Split s=0: kt in [0,qt]; s=1:
// kt in [qt+1, 2qt+1] (wave guard kt<=2qt+w). Register prefetch of tile kt+1
// overlaps compute of kt. K in granule-major LDS (2-way conflicts only).
// Partials: unnormalized O (bf16) + m,l (f32) per q-row per split.
// ---------------------------------------------------------------------------
#define SCALE_L2E 0.180336880f   // 0.125 * log2(e)

__global__ __launch_bounds__(128) void attn_bf16(
    const ushort* __restrict__ Qkv, ushort* __restrict__ Opart, float* __restrict__ Ml)
{
    __shared__ __align__(16) ushort Ks[8][64][8];   // [k-granule][krow][8]
    __shared__ __align__(16) ushort Vt[64][72];     // [d][krow]

    const int x = blockIdx.x;               // heavy blocks first
    const int qt = 15 - (x >> 6);
    const int inner = x & 63;
    const int bh = inner & 31, s = inner >> 5;
    const int h = bh & 15, b = bh >> 4;

    const int tid = threadIdx.x;
    const int w = tid >> 6, lane = tid & 63;
    const int lq = lane & 15, quad = lane >> 4;
    const int boff = b * NB_L;
    const int qrow_base = qt * 128 + w * 64;

    // Q fragments in registers: k = 32*sb + 8*quad + jj, row = qg*16+lq
    s8v qf[4][2];
#pragma unroll
    for (int qg = 0; qg < 4; ++qg)
#pragma unroll
        for (int sb = 0; sb < 2; ++sb)
            qf[qg][sb] = *(const s8v*)(Qkv + (size_t)(boff + qrow_base + qg * 16 + lq) * GN
                                       + h * 64 + sb * 32 + quad * 8);

    f4v o[4][4];   // O^T [dg][qg], d = dg*16+quad*4+r, q-row = qg*16+lq
#pragma unroll
    for (int dg = 0; dg < 4; ++dg)
#pragma unroll
        for (int qg = 0; qg < 4; ++qg) o[dg][qg] = 0.f;
    float m_s[4], l_s[4];
#pragma unroll
    for (int qg = 0; qg < 4; ++qg) { m_s[qg] = -INFINITY; l_s[qg] = 0.f; }

    const int kt_lo = s ? (qt + 1) : 0;
    const int kt_hi = s ? (2 * qt + 1) : qt;    // inclusive staging range

    // staging mappings
    const int krow_s = tid >> 1, g0 = (tid & 1) * 4;   // K: row, 4 granules
    const int pr = tid >> 2, dc0 = (tid & 3) * 16;     // V: row-pair, d-chunk

    s8v kreg[4], vreg[4];
    {
        const ushort* kp = Qkv + (size_t)(boff + kt_lo * 64 + krow_s) * GN + 1024 + h * 64 + g0 * 8;
#pragma unroll
        for (int i = 0; i < 4; ++i) kreg[i] = *(const s8v*)(kp + 8 * i);
        const ushort* vp = Qkv + (size_t)(boff + kt_lo * 64 + 2 * pr) * GN + 2048 + h * 64 + dc0;
        vreg[0] = *(const s8v*)vp;        vreg[1] = *(const s8v*)(vp + 8);
        vreg[2] = *(const s8v*)(vp + GN); vreg[3] = *(const s8v*)(vp + GN + 8);
    }

    for (int kt = kt_lo; kt <= kt_hi; ++kt) {
        __syncthreads();   // previous compute done with LDS
#pragma unroll
        for (int i = 0; i < 4; ++i)
            *(s8v*)&Ks[g0 + i][krow_s][0] = kreg[i];
#pragma unroll
        for (int j = 0; j < 16; ++j) {
            const unsigned short lo = (unsigned short)((j < 8) ? vreg[0][j] : vreg[1][j - 8]);
            const unsigned short hi = (unsigned short)((j < 8) ? vreg[2][j] : vreg[3][j - 8]);
            *(unsigned int*)&Vt[dc0 + j][2 * pr] = (unsigned int)lo | ((unsigned int)hi << 16);
        }
        __syncthreads();

        if (kt < kt_hi) {  // prefetch next tile (overlaps with compute below)
            const ushort* kp = Qkv + (size_t)(boff + (kt + 1) * 64 + krow_s) * GN + 1024 + h * 64 + g0 * 8;
#pragma unroll
            for (int i = 0; i < 4; ++i) kreg[i] = *(const s8v*)(kp + 8 * i);
            const ushort* vp = Qkv + (size_t)(boff + (kt + 1) * 64 + 2 * pr) * GN + 2048 + h * 64 + dc0;
            vreg[0] = *(const s8v*)vp;        vreg[1] = *(const s8v*)(vp + 8);
            vreg[2] = *(const s8v*)(vp + GN); vreg[3] = *(const s8v*)(vp + GN + 8);
        }

        if (kt <= 2 * qt + w) {
            // ---- S^T = K · Q^T ----
            f4v st[4][4];
#pragma unroll
            for (int kg = 0; kg < 4; ++kg)
#pragma unroll
                for (int qg = 0; qg < 4; ++qg) st[kg][qg] = 0.f;
#pragma unroll
            for (int kg = 0; kg < 4; ++kg) {
#pragma unroll
                for (int sb = 0; sb < 2; ++sb) {
                    const s8v af = *(const s8v*)&Ks[sb * 4 + quad][kg * 16 + lq][0];
#pragma unroll
                    for (int qg = 0; qg < 4; ++qg)
                        st[kg][qg] = MFMA_16x16x32(af, qf[qg][sb], st[kg][qg]);
                }
            }
            // causal mask (diagonal tile only)
            if (kt == 2 * qt + w) {
#pragma unroll
                for (int kg = 0; kg < 4; ++kg)
#pragma unroll
                    for (int qg = 0; qg < 4; ++qg) {
                        const int qrow = qrow_base + qg * 16 + lq;
#pragma unroll
                        for (int r = 0; r < 4; ++r)
                            if (kt * 64 + kg * 16 + quad * 4 + r > qrow)
                                st[kg][qg][r] = -INFINITY;
                    }
            }
            // ---- online softmax per q-column ----
#pragma unroll
            for (int qg = 0; qg < 4; ++qg) {
                float mx = -INFINITY;
#pragma unroll
                for (int kg = 0; kg < 4; ++kg)
#pragma unroll
                    for (int r = 0; r < 4; ++r) mx = fmaxf(mx, st[kg][qg][r]);
                mx = fmaxf(mx, __shfl_xor(mx, 16));
                mx = fmaxf(mx, __shfl_xor(mx, 32));
                const float mnew = fmaxf(m_s[qg], mx);
                const float alpha = exp2f((m_s[qg] - mnew) * SCALE_L2E);
                m_s[qg] = mnew;
                const float mc = mnew * SCALE_L2E;
                float sum = 0.f;
#pragma unroll
                for (int kg = 0; kg < 4; ++kg)
#pragma unroll
                    for (int r = 0; r < 4; ++r) {
                        const float p = exp2f(fmaf(st[kg][qg][r], SCALE_L2E, -mc));
                        st[kg][qg][r] = p;
                        sum += p;
                    }
                sum += __shfl_xor(sum, 16);
                sum += __shfl_xor(sum, 32);
                l_s[qg] = l_s[qg] * alpha + sum;
#pragma unroll
                for (int dg = 0; dg < 4; ++dg) o[dg][qg] *= alpha;
            }
            // ---- O^T += V^T · P^T ----
#pragma unroll
            for (int ks = 0; ks < 4; ++ks) {
                s4v pb[4];
#pragma unroll
                for (int qg = 0; qg < 4; ++qg) {
                    union { s4v v; uint2 u; } c;
                    c.u.x = bfpk(st[ks][qg][0], st[ks][qg][1]);
                    c.u.y = bfpk(st[ks][qg][2], st[ks][qg][3]);
                    pb[qg] = c.v;
                }
#pragma unroll
                for (int dg = 0; dg < 4; ++dg) {
                    const s4v va = *(const s4v*)&Vt[dg * 16 + lq][ks * 16 + quad * 4];
#pragma unroll
                    for (int qg = 0; qg < 4; ++qg)
                        o[dg][qg] = MFMA_16x16x16(va, pb[qg], o[dg][qg]);
                }
            }
        }
    }

    // ---- store partials (unnormalized O as bf16; m,l as f32) ----
#pragma unroll
    for (int qg = 0; qg < 4; ++qg) {
        const size_t prow = (size_t)(s * 32 + bh) * 2048 + qrow_base + qg * 16 + lq;
#pragma unroll
        for (int dg = 0; dg < 4; ++dg) {
            const int d = dg * 16 + quad * 4;
            *(unsigned int*)&Opart[prow * 64 + d]     = bfpk(o[dg][qg][0], o[dg][qg][1]);
            *(unsigned int*)&Opart[prow * 64 + d + 2] = bfpk(o[dg][qg][2], o[dg][qg][3]);
        }
        if (quad == 0) {
            Ml[prow * 2]     = m_s[qg] * SCALE_L2E;   // exp2-units
            Ml[prow * 2 + 1] = l_s[qg];
        }
    }
}

// ---------------------------------------------------------------------------
// Combine the two K-split partials -> final f32 output [B, L, D].
// ---------------------------------------------------------------------------
__global__ __launch_bounds__(256) void attn_combine(
    const ushort* __restrict__ Opart, const float* __restrict__ Ml, float* __restrict__ Out)
{
    const int id = blockIdx.x * 256 + threadIdx.x;  // 65536 rows * 16 chunks
    const int row = id >> 4, c4 = (id & 15) * 4;
    const float m0 = Ml[(size_t)row * 2],             l0 = Ml[(size_t)row * 2 + 1];
    const float m1 = Ml[(size_t)(row + NROWS) * 2],   l1 = Ml[(size_t)(row + NROWS) * 2 + 1];
    const float M = fmaxf(m0, m1);
    float w0 = exp2f(m0 - M), w1 = exp2f(m1 - M);
    const float inv = 1.0f / fmaf(l0, w0, l1 * w1);
    w0 *= inv; w1 *= inv;

    const s4v a = *(const s4v*)&Opart[(size_t)row * 64 + c4];
    const s4v c = *(const s4v*)&Opart[(size_t)(row + NROWS) * 64 + c4];
    float4 v;
    v.x = w0 * bf2f((unsigned short)a[0]) + w1 * bf2f((unsigned short)c[0]);
    v.y = w0 * bf2f((unsigned short)a[1]) + w1 * bf2f((unsigned short)c[1]);
    v.z = w0 * bf2f((unsigned short)a[2]) + w1 * bf2f((unsigned short)c[2]);
    v.w = w0 * bf2f((unsigned short)a[3]) + w1 * bf2f((unsigned short)c[3]);

    const int bh = row >> 11, qrow = row & 2047;
    const int b = bh >> 4, h = bh & 15;
    *(float4*)(Out + ((size_t)(b * 2048 + qrow)) * 1024 + h * 64 + c4) = v;
}

// ---------------------------------------------------------------------------
extern "C" void kernel_launch(void* const* d_in, const int* in_sizes, int n_in,
                              void* d_out, int out_size, void* d_ws, size_t ws_size,
                              hipStream_t stream)
{
    const float* x  = (const float*)d_in[0];  // [2,2048,1024] f32
    const float* wq = (const float*)d_in[1];  // [1024,3072] f32
    float* out = (float*)d_out;               // [2,2048,1024] f32

    ushort* wsp  = (ushort*)d_ws;
    ushort* qkvb = wsp;                            // 25.2 MB
    ushort* xb   = wsp + (size_t)GM * GN;          //  8.4 MB (dead after GEMM)
    ushort* wt   = xb + (size_t)GM * GK;           //  6.3 MB (dead after GEMM)
    // attention partials overlay xb/wt (alive only after GEMM):
    ushort* opart = wsp + (size_t)GM * GN;         // 2*65536*64 bf16 = 16.8 MB
    float*  ml    = (float*)(opart + (size_t)2 * NROWS * 64);  // 1.05 MB

    conv_x<<<GM * GK / (256 * 8), 256, 0, stream>>>(x, xb);
    conv_wt<<<dim3(GK / 64, GN / 64), 256, 0, stream>>>(wq, wt);
    qkv_gemm_bf16<<<dim3(GN / 128, GM / 128), 256, 0, stream>>>(xb, wt, qkvb);
    attn_bf16<<<1024, 128, 0, stream>>>(qkvb, opart, ml);
    attn_combine<<<NROWS * 16 / 256, 256, 0, stream>>>(opart, ml, out);
}